// Round 20
// baseline (30.580 us; speedup 1.0000x reference)
//
#include <hip/hip_runtime.h>

#define DD 256
#define TQ 512
#define TK 1024
#define NG 64            // d-quads (256/4)
#define C2 2.88539008177792681472f   // 2*log2(e)

typedef short bf16x8 __attribute__((ext_vector_type(8)));
typedef short bf16x4 __attribute__((ext_vector_type(4)));
typedef float f32x4  __attribute__((ext_vector_type(4)));
typedef float f32x16 __attribute__((ext_vector_type(16)));

__device__ __forceinline__ float fexp2(float x){ return __builtin_amdgcn_exp2f(x); }
__device__ __forceinline__ float frcp (float x){ return __builtin_amdgcn_rcpf(x); }
__device__ __forceinline__ short rne_bf16(float x){
    union { float f; unsigned u; } v; v.f = x;
    unsigned r = v.u + 0x7FFFu + ((v.u >> 16) & 1u);
    return (short)(r >> 16);
}

// -------- proj + featurize, v3 (unchanged from R19) --------
__global__ __launch_bounds__(256) void proj_feat_kernel(
    const float* __restrict__ query, const float* __restrict__ key,
    const float* __restrict__ Wq, const float* __restrict__ Wk,
    const float* __restrict__ vw,
    unsigned short* __restrict__ phid, unsigned short* __restrict__ phin,
    unsigned short* __restrict__ psi)
{
    __shared__ short Wl[16 * 264];      // [wrow][d], bf16
    __shared__ short Xl[32 * 264];      // [token_local][d], bf16
    __shared__ float xch[2][64][5];     // partial-acc exchange
    __shared__ float et[2][16][21];     // E-tile bounce

    const int tid = threadIdx.x;
    const int w = tid >> 6, l = tid & 63;
    const int ct = blockIdx.x & 15, chunk = blockIdx.x >> 4;   // chunk 0..47
    const int qside = (chunk < 16);
    const float* X; const float* W; unsigned short* outd; int NT, tok0;
    if (qside) { X = query + chunk * 32 * DD; W = Wq; outd = phid; NT = TQ; tok0 = chunk * 32; }
    else { X = key + (chunk - 16) * 32 * DD; W = Wk; outd = psi; NT = TK; tok0 = (chunk - 16) * 32; }
    const float* Wp0 = W + ct * 16 * DD;

    #pragma unroll
    for (int rep = 0; rep < 4; ++rep) {
        int idx = rep * 256 + tid;                 // float4 index
        float4 f4 = ((const float4*)Wp0)[idx];
        int row = idx >> 6, dc = (idx & 63) * 4;
        bf16x4 b = { rne_bf16(f4.x), rne_bf16(f4.y), rne_bf16(f4.z), rne_bf16(f4.w) };
        *(bf16x4*)&Wl[row * 264 + dc] = b;
    }
    #pragma unroll
    for (int rep = 0; rep < 8; ++rep) {
        int idx = rep * 256 + tid;
        float4 f4 = ((const float4*)X)[idx];
        int row = idx >> 6, dc = (idx & 63) * 4;
        bf16x4 b = { rne_bf16(f4.x), rne_bf16(f4.y), rne_bf16(f4.z), rne_bf16(f4.w) };
        *(bf16x4*)&Xl[row * 264 + dc] = b;
    }
    __syncthreads();

    const int pair = w >> 1, khalf = w & 1;
    const int lr = l & 15, kg = (l >> 4) * 8;
    const int arow = pair * 16 + lr;

    f32x4 acc = {0.f, 0.f, 0.f, 0.f};
    #pragma unroll
    for (int k0 = 0; k0 < 4; ++k0) {
        const int kk = khalf * 128 + k0 * 32 + kg;
        bf16x8 af = *(const bf16x8*)&Xl[arow * 264 + kk];
        bf16x8 bf = *(const bf16x8*)&Wl[lr * 264 + kk];
        acc = __builtin_amdgcn_mfma_f32_16x16x32_bf16(af, bf, acc, 0, 0, 0);
    }

    if (khalf == 1) {
        #pragma unroll
        for (int r = 0; r < 4; ++r) xch[pair][l][r] = acc[r];
    }
    __syncthreads();
    if (khalf == 0) {
        #pragma unroll
        for (int r = 0; r < 4; ++r) acc[r] += xch[pair][l][r];

        float* etp = &et[pair][0][0];
        #pragma unroll
        for (int r = 0; r < 4; ++r)
            etp[lr * 21 + (l >> 4) * 4 + r] = fexp2(C2 * acc[r]);

        const int tl = l & 15, gq = l >> 4;
        float E0 = etp[(gq * 4 + 0) * 21 + tl];
        float E1 = etp[(gq * 4 + 1) * 21 + tl];
        float E2 = etp[(gq * 4 + 2) * 21 + tl];
        float E3 = etp[(gq * 4 + 3) * 21 + tl];
        float p[16];
        p[0]=1.f;   p[1]=E0;      p[2]=E1;      p[3]=E0*E1;
        p[4]=E2;    p[5]=E0*E2;   p[6]=E1*E2;   p[7]=p[3]*E2;
        p[8]=E3;    p[9]=E0*E3;   p[10]=E1*E3;  p[11]=p[3]*E3;
        p[12]=E2*E3;p[13]=p[5]*E3;p[14]=p[6]*E3;p[15]=p[7]*E3;

        const int g = ct * 4 + gq;
        const int token = tok0 + pair * 16 + tl;
        const int base = (g * NT + token) * 16;
        bf16x8 w0, w1;
        #pragma unroll
        for (int j = 0; j < 8; ++j) { w0[j] = rne_bf16(p[j]); w1[j] = rne_bf16(p[8+j]); }
        *(bf16x8*)&outd[base]     = w0;
        *(bf16x8*)&outd[base + 8] = w1;

        if (qside) {
            float4 v4 = *(const float4*)&vw[4 * g];
            float v0 = v4.x, v1 = v4.y, v2 = v4.z, v3 = v4.w;
            float sall = v0 + v1 + v2 + v3;
            float c[16];
            c[0]=sall;      c[1]=sall-v0;      c[2]=sall-v1;      c[3]=c[1]-v1;
            c[4]=sall-v2;   c[5]=c[1]-v2;      c[6]=c[2]-v2;      c[7]=c[3]-v2;
            c[8]=sall-v3;   c[9]=c[1]-v3;      c[10]=c[2]-v3;     c[11]=c[3]-v3;
            c[12]=c[4]-v3;  c[13]=c[5]-v3;     c[14]=c[6]-v3;     c[15]=0.f;
            bf16x8 n0, n1;
            #pragma unroll
            for (int j = 0; j < 8; ++j) { n0[j] = rne_bf16(c[j]*p[j]); n1[j] = rne_bf16(c[8+j]*p[8+j]); }
            *(bf16x8*)&phin[base]     = n0;
            *(bf16x8*)&phin[base + 8] = n1;
        }
    }
}

#define MERGE16(NA, DA, NQ, DQ) { f32x16 _t = (NQ) * (DA); (NA) = (NA) * (DQ) + _t; (DA) = (DA) * (DQ); }

// -------- scores v2: 32q x 64k per block, 16 waves, q-fragment register reuse --------
// 256 blocks x 1024 threads (4 waves/SIMD). Wave w owns quads w*4..w*4+3: loads its
// 8 q-fragments ONCE (32 VGPR), reuses across 2 k-subtiles -> fragment traffic
// 98 MB -> 65 MB. Per wave per subtile: one 4-quad merge chain + 1 rcp (same
// grouping as R15: 16 groups of 4 -> absmax unchanged). Two-pass LDS reduce.
__global__ __launch_bounds__(1024, 4) void scores_kernel(
    const unsigned short* __restrict__ phid, const unsigned short* __restrict__ phin,
    const unsigned short* __restrict__ psi,  const float* __restrict__ vw,
    float* __restrict__ out)
{
    __shared__ float red[8][64][17];
    __shared__ float vsum_s;
    const int qb = blockIdx.x & 15, kb = blockIdx.x >> 4;   // 16 q-tiles x 16 k-tiles
    const int tid = threadIdx.x;
    const int w = tid >> 6, l = tid & 63, lr31 = l & 31, lh = l >> 5;

    if (tid < 64) {
        float4 vv = *(const float4*)&vw[tid * 4];
        float s = vv.x + vv.y + vv.z + vv.w;
        #pragma unroll
        for (int m = 1; m < 64; m <<= 1) s += __shfl_xor(s, m);
        if (tid == 0) vsum_s = s;
    }

    const int qt  = qb * 32 + lr31;        // A row token
    const int kt0 = kb * 64 + lr31;        // B col token, subtile 0
    const int fo  = lh * 8;                // feature offset
    const f32x16 z = {0.f,0.f,0.f,0.f,0.f,0.f,0.f,0.f,0.f,0.f,0.f,0.f,0.f,0.f,0.f,0.f};
    const int g0 = w * 4;

    // q-fragments for this wave's 4 quads, loaded once
    bf16x8 afd[4], afn[4];
    #pragma unroll
    for (int qi = 0; qi < 4; ++qi) {
        afd[qi] = *(const bf16x8*)&phid[((g0 + qi) * TQ + qt) * 16 + fo];
        afn[qi] = *(const bf16x8*)&phin[((g0 + qi) * TQ + qt) * 16 + fo];
    }

    f32x16 a0, a1;
    {   // k-subtile 0
        f32x16 nA, dA;
        #pragma unroll
        for (int qi = 0; qi < 4; ++qi) {
            bf16x8 bp = *(const bf16x8*)&psi[((g0 + qi) * TK + kt0) * 16 + fo];
            f32x16 d = __builtin_amdgcn_mfma_f32_32x32x16_bf16(afd[qi], bp, z, 0, 0, 0);
            f32x16 n = __builtin_amdgcn_mfma_f32_32x32x16_bf16(afn[qi], bp, z, 0, 0, 0);
            if (qi == 0) { nA = n; dA = d; }
            else MERGE16(nA, dA, n, d);
        }
        #pragma unroll
        for (int r = 0; r < 16; ++r) a0[r] = nA[r] * frcp(dA[r]);
    }
    {   // k-subtile 1
        f32x16 nA, dA;
        #pragma unroll
        for (int qi = 0; qi < 4; ++qi) {
            bf16x8 bp = *(const bf16x8*)&psi[((g0 + qi) * TK + kt0 + 32) * 16 + fo];
            f32x16 d = __builtin_amdgcn_mfma_f32_32x32x16_bf16(afd[qi], bp, z, 0, 0, 0);
            f32x16 n = __builtin_amdgcn_mfma_f32_32x32x16_bf16(afn[qi], bp, z, 0, 0, 0);
            if (qi == 0) { nA = n; dA = d; }
            else MERGE16(nA, dA, n, d);
        }
        #pragma unroll
        for (int r = 0; r < 16; ++r) a1[r] = nA[r] * frcp(dA[r]);
    }

    const float vsum = vsum_s;   // LDS-written at start; used after barriers below
    // ---- pass 0: k-subtile 0 ----
    if (w >= 8) {
        #pragma unroll
        for (int r = 0; r < 16; ++r) red[w - 8][l][r] = a0[r];
    }
    __syncthreads();
    if (w < 8) {
        #pragma unroll
        for (int r = 0; r < 16; ++r) red[w][l][r] += a0[r];
    }
    __syncthreads();
    {
        const int r = w;           // 0..15
        float sum = 0.f;
        #pragma unroll
        for (int ww = 0; ww < 8; ++ww) sum += red[ww][l][r];
        const int row = qb * 32 + (r & 3) + 8 * (r >> 2) + 4 * lh;
        const int col = kb * 64 + lr31;
        out[row * TK + col] = fmaf(-2.f, sum, vsum);
    }
    __syncthreads();
    // ---- pass 1: k-subtile 1 ----
    if (w >= 8) {
        #pragma unroll
        for (int r = 0; r < 16; ++r) red[w - 8][l][r] = a1[r];
    }
    __syncthreads();
    if (w < 8) {
        #pragma unroll
        for (int r = 0; r < 16; ++r) red[w][l][r] += a1[r];
    }
    __syncthreads();
    {
        const int r = w;
        float sum = 0.f;
        #pragma unroll
        for (int ww = 0; ww < 8; ++ww) sum += red[ww][l][r];
        const int row = qb * 32 + (r & 3) + 8 * (r >> 2) + 4 * lh;
        const int col = kb * 64 + 32 + lr31;
        out[row * TK + col] = fmaf(-2.f, sum, vsum);
    }
}

extern "C" void kernel_launch(void* const* d_in, const int* in_sizes, int n_in,
                              void* d_out, int out_size, void* d_ws, size_t ws_size,
                              hipStream_t stream) {
    const float* query = (const float*)d_in[0];   // [512,256]
    const float* key   = (const float*)d_in[1];   // [1024,256]
    // d_in[2] = value, unused by the reference
    const float* Wq    = (const float*)d_in[3];   // [256,256]
    const float* Wk    = (const float*)d_in[4];   // [256,256]
    const float* vw    = (const float*)d_in[5];   // [1,256]
    float* out = (float*)d_out;                   // [512,1024]

    char* ws = (char*)d_ws;
    unsigned short* phid = (unsigned short*)ws;               // 64x512x16 bf16 (1 MB)
    unsigned short* phin = (unsigned short*)(ws + 1048576);   // 64x512x16 bf16 (1 MB)
    unsigned short* psi  = (unsigned short*)(ws + 2097152);   // 64x1024x16 bf16 (2 MB)

    proj_feat_kernel<<<768, 256, 0, stream>>>(query, key, Wq, Wk, vw, phid, phin, psi);
    scores_kernel<<<256, 1024, 0, stream>>>(phid, phin, psi, vw, out);
}

// Round 21
// 19.003 us; speedup vs baseline: 1.6092x; 1.6092x over previous
//
#include <hip/hip_runtime.h>

#define DD 256
#define TQ 512
#define TK 1024
#define NG 64            // d-quads (256/4)
#define C2 2.88539008177792681472f   // 2*log2(e)

typedef short bf16x8 __attribute__((ext_vector_type(8)));
typedef short bf16x4 __attribute__((ext_vector_type(4)));
typedef float f32x4  __attribute__((ext_vector_type(4)));
typedef float f32x16 __attribute__((ext_vector_type(16)));

__device__ __forceinline__ float fexp2(float x){ return __builtin_amdgcn_exp2f(x); }
__device__ __forceinline__ float frcp (float x){ return __builtin_amdgcn_rcpf(x); }
__device__ __forceinline__ short rne_bf16(float x){
    union { float f; unsigned u; } v; v.f = x;
    unsigned r = v.u + 0x7FFFu + ((v.u >> 16) & 1u);
    return (short)(r >> 16);
}

// -------- proj + featurize, v3: coalesced LDS staging + 2-wave K-split (R19) --------
__global__ __launch_bounds__(256) void proj_feat_kernel(
    const float* __restrict__ query, const float* __restrict__ key,
    const float* __restrict__ Wq, const float* __restrict__ Wk,
    const float* __restrict__ vw,
    unsigned short* __restrict__ phid, unsigned short* __restrict__ phin,
    unsigned short* __restrict__ psi)
{
    __shared__ short Wl[16 * 264];      // [wrow][d], bf16
    __shared__ short Xl[32 * 264];      // [token_local][d], bf16
    __shared__ float xch[2][64][5];     // partial-acc exchange
    __shared__ float et[2][16][21];     // E-tile bounce

    const int tid = threadIdx.x;
    const int w = tid >> 6, l = tid & 63;
    const int ct = blockIdx.x & 15, chunk = blockIdx.x >> 4;   // chunk 0..47
    const int qside = (chunk < 16);
    const float* X; const float* W; unsigned short* outd; int NT, tok0;
    if (qside) { X = query + chunk * 32 * DD; W = Wq; outd = phid; NT = TQ; tok0 = chunk * 32; }
    else { X = key + (chunk - 16) * 32 * DD; W = Wk; outd = psi; NT = TK; tok0 = (chunk - 16) * 32; }
    const float* Wp0 = W + ct * 16 * DD;

    #pragma unroll
    for (int rep = 0; rep < 4; ++rep) {
        int idx = rep * 256 + tid;                 // float4 index
        float4 f4 = ((const float4*)Wp0)[idx];
        int row = idx >> 6, dc = (idx & 63) * 4;
        bf16x4 b = { rne_bf16(f4.x), rne_bf16(f4.y), rne_bf16(f4.z), rne_bf16(f4.w) };
        *(bf16x4*)&Wl[row * 264 + dc] = b;
    }
    #pragma unroll
    for (int rep = 0; rep < 8; ++rep) {
        int idx = rep * 256 + tid;
        float4 f4 = ((const float4*)X)[idx];
        int row = idx >> 6, dc = (idx & 63) * 4;
        bf16x4 b = { rne_bf16(f4.x), rne_bf16(f4.y), rne_bf16(f4.z), rne_bf16(f4.w) };
        *(bf16x4*)&Xl[row * 264 + dc] = b;
    }
    __syncthreads();

    const int pair = w >> 1, khalf = w & 1;
    const int lr = l & 15, kg = (l >> 4) * 8;
    const int arow = pair * 16 + lr;

    f32x4 acc = {0.f, 0.f, 0.f, 0.f};
    #pragma unroll
    for (int k0 = 0; k0 < 4; ++k0) {
        const int kk = khalf * 128 + k0 * 32 + kg;
        bf16x8 af = *(const bf16x8*)&Xl[arow * 264 + kk];
        bf16x8 bf = *(const bf16x8*)&Wl[lr * 264 + kk];
        acc = __builtin_amdgcn_mfma_f32_16x16x32_bf16(af, bf, acc, 0, 0, 0);
    }

    if (khalf == 1) {
        #pragma unroll
        for (int r = 0; r < 4; ++r) xch[pair][l][r] = acc[r];
    }
    __syncthreads();
    if (khalf == 0) {
        #pragma unroll
        for (int r = 0; r < 4; ++r) acc[r] += xch[pair][l][r];

        float* etp = &et[pair][0][0];
        #pragma unroll
        for (int r = 0; r < 4; ++r)
            etp[lr * 21 + (l >> 4) * 4 + r] = fexp2(C2 * acc[r]);

        const int tl = l & 15, gq = l >> 4;
        float E0 = etp[(gq * 4 + 0) * 21 + tl];
        float E1 = etp[(gq * 4 + 1) * 21 + tl];
        float E2 = etp[(gq * 4 + 2) * 21 + tl];
        float E3 = etp[(gq * 4 + 3) * 21 + tl];
        float p[16];
        p[0]=1.f;   p[1]=E0;      p[2]=E1;      p[3]=E0*E1;
        p[4]=E2;    p[5]=E0*E2;   p[6]=E1*E2;   p[7]=p[3]*E2;
        p[8]=E3;    p[9]=E0*E3;   p[10]=E1*E3;  p[11]=p[3]*E3;
        p[12]=E2*E3;p[13]=p[5]*E3;p[14]=p[6]*E3;p[15]=p[7]*E3;

        const int g = ct * 4 + gq;
        const int token = tok0 + pair * 16 + tl;
        const int base = (g * NT + token) * 16;
        bf16x8 w0, w1;
        #pragma unroll
        for (int j = 0; j < 8; ++j) { w0[j] = rne_bf16(p[j]); w1[j] = rne_bf16(p[8+j]); }
        *(bf16x8*)&outd[base]     = w0;
        *(bf16x8*)&outd[base + 8] = w1;

        if (qside) {
            float4 v4 = *(const float4*)&vw[4 * g];
            float v0 = v4.x, v1 = v4.y, v2 = v4.z, v3 = v4.w;
            float sall = v0 + v1 + v2 + v3;
            float c[16];
            c[0]=sall;      c[1]=sall-v0;      c[2]=sall-v1;      c[3]=c[1]-v1;
            c[4]=sall-v2;   c[5]=c[1]-v2;      c[6]=c[2]-v2;      c[7]=c[3]-v2;
            c[8]=sall-v3;   c[9]=c[1]-v3;      c[10]=c[2]-v3;     c[11]=c[3]-v3;
            c[12]=c[4]-v3;  c[13]=c[5]-v3;     c[14]=c[6]-v3;     c[15]=0.f;
            bf16x8 n0, n1;
            #pragma unroll
            for (int j = 0; j < 8; ++j) { n0[j] = rne_bf16(c[j]*p[j]); n1[j] = rne_bf16(c[8+j]*p[8+j]); }
            *(bf16x8*)&phin[base]     = n0;
            *(bf16x8*)&phin[base + 8] = n1;
        }
    }
}

#define MERGE16(NA, DA, NQ, DQ) { f32x16 _t = (NQ) * (DA); (NA) = (NA) * (DQ) + _t; (DA) = (DA) * (DQ); }

// -------- scores via 32x32x16 MFMA (R15/R19 version — best verified) --------
__global__ __launch_bounds__(512, 2) void scores_kernel(
    const unsigned short* __restrict__ phid, const unsigned short* __restrict__ phin,
    const unsigned short* __restrict__ psi,  const float* __restrict__ vw,
    float* __restrict__ out)
{
    __shared__ float red[8][64][17];
    __shared__ float vsum_s;
    const int id = blockIdx.x;
    const int qb = (id & 7) + 8 * (id >> 8);
    const int kb = (id >> 3) & 31;
    const int tid = threadIdx.x;
    const int w = tid >> 6, l = tid & 63, lr31 = l & 31, lh = l >> 5;

    if (tid < 64) {
        float4 vv = *(const float4*)&vw[tid * 4];
        float s = vv.x + vv.y + vv.z + vv.w;
        #pragma unroll
        for (int m = 1; m < 64; m <<= 1) s += __shfl_xor(s, m);
        if (tid == 0) vsum_s = s;
    }

    const int qt = qb * 32 + lr31;     // A row token
    const int kt = kb * 32 + lr31;     // B col token
    const int fo = lh * 8;             // feature offset
    const f32x16 z = {0.f,0.f,0.f,0.f,0.f,0.f,0.f,0.f,0.f,0.f,0.f,0.f,0.f,0.f,0.f,0.f};

    f32x16 a = z;
    #pragma unroll
    for (int hx = 0; hx < 2; ++hx) {
        f32x16 nA, dA;
        #pragma unroll
        for (int qi = 0; qi < 4; ++qi) {
            const int g = w * 8 + hx * 4 + qi;
            bf16x8 afd = *(const bf16x8*)&phid[(g * TQ + qt) * 16 + fo];
            bf16x8 afn = *(const bf16x8*)&phin[(g * TQ + qt) * 16 + fo];
            bf16x8 bp  = *(const bf16x8*)&psi [(g * TK + kt) * 16 + fo];
            f32x16 d = __builtin_amdgcn_mfma_f32_32x32x16_bf16(afd, bp, z, 0, 0, 0);
            f32x16 n = __builtin_amdgcn_mfma_f32_32x32x16_bf16(afn, bp, z, 0, 0, 0);
            if (qi == 0) { nA = n; dA = d; }
            else MERGE16(nA, dA, n, d);
        }
        #pragma unroll
        for (int r = 0; r < 16; ++r)
            a[r] = fmaf(nA[r], frcp(dA[r]), a[r]);
    }

    #pragma unroll
    for (int r = 0; r < 16; ++r) red[w][l][r] = a[r];
    __syncthreads();

    const float vsum = vsum_s;
    const int lane = tid & 63, rbase = (tid >> 6) * 2;
    const int lane_lh = lane >> 5, lane_lr = lane & 31;
    #pragma unroll
    for (int rr = 0; rr < 2; ++rr) {
        const int r = rbase + rr;
        float sum = 0.f;
        #pragma unroll
        for (int ww = 0; ww < 8; ++ww) sum += red[ww][lane][r];
        const int row = qb * 32 + (r & 3) + 8 * (r >> 2) + 4 * lane_lh;
        const int col = kb * 32 + lane_lr;
        out[row * TK + col] = fmaf(-2.f, sum, vsum);
    }
}

extern "C" void kernel_launch(void* const* d_in, const int* in_sizes, int n_in,
                              void* d_out, int out_size, void* d_ws, size_t ws_size,
                              hipStream_t stream) {
    const float* query = (const float*)d_in[0];   // [512,256]
    const float* key   = (const float*)d_in[1];   // [1024,256]
    // d_in[2] = value, unused by the reference
    const float* Wq    = (const float*)d_in[3];   // [256,256]
    const float* Wk    = (const float*)d_in[4];   // [256,256]
    const float* vw    = (const float*)d_in[5];   // [1,256]
    float* out = (float*)d_out;                   // [512,1024]

    char* ws = (char*)d_ws;
    unsigned short* phid = (unsigned short*)ws;               // 64x512x16 bf16 (1 MB)
    unsigned short* phin = (unsigned short*)(ws + 1048576);   // 64x512x16 bf16 (1 MB)
    unsigned short* psi  = (unsigned short*)(ws + 2097152);   // 64x1024x16 bf16 (2 MB)

    proj_feat_kernel<<<768, 256, 0, stream>>>(query, key, Wq, Wk, vw, phid, phin, psi);
    scores_kernel<<<512, 512, 0, stream>>>(phid, phin, psi, vw, out);
}